// Round 12
// baseline (26.051 us; speedup 1.0000x reference)
//
#include <hip/hip_runtime.h>
#include <hip/hip_fp16.h>
#include <math.h>

// Problem constants (match reference)
#define Bb   16
#define Cc   3
#define Hh   64
#define Ww   64
#define Kk   32
#define Ss   32
#define OHh  60
#define OWw  60
#define Pp   3600
#define ROWS 34            // staged rows per block: 30 output rows + R-1
#define OHSUB 30
#define NGRP 450
#define TPB  256

// fp16 LDS layout (dword units): row = 33 dwords. Bank stride/row = 1 ->
// oh-major lanes conflict-free. Two copies (shift 0/1 col): every 4-px
// gather is one ds_read2_b32 (2 adjacent dwords).
#define DWROW  33
#define DWC    (ROWS * DWROW)   // 1122 dwords per channel
#define DWCOPY (Cc * DWC)       // 3366 dwords per copy

typedef float vf4 __attribute__((ext_vector_type(4)));
typedef float vf4u __attribute__((ext_vector_type(4), aligned(4)));

#define SB __builtin_amdgcn_sched_barrier(0)

static __device__ __forceinline__ vf4 vsplat(float s) { return (vf4){s, s, s, s}; }

// combine: y = c0 + a*dA + b*dB + a*b*dAB  (c = {c0, dA, dB, dAB})
static __device__ __forceinline__ vf4 comb(vf4 a, vf4 b, vf4 c) {
    const vf4 t = __builtin_elementwise_fma(b, vsplat(c.w), vsplat(c.y));
    const vf4 u = __builtin_elementwise_fma(b, vsplat(c.z), vsplat(c.x));
    return __builtin_elementwise_fma(a, t, u);
}

static __device__ __forceinline__ unsigned int pkh(float lo, float hi) {
    __half2 h = __floats2half2_rn(lo, hi);
    return *reinterpret_cast<unsigned int*>(&h);
}

// deferred conversion: packed 4 halfs (2 dwords) -> vf4 at consume point
static __device__ __forceinline__ vf4 cvt4(uint2 u) {
    const __half2 hl = *reinterpret_cast<const __half2*>(&u.x);
    const __half2 hh = *reinterpret_cast<const __half2*>(&u.y);
    const float2 fl = __half22float2(hl);
    const float2 fh = __half22float2(hh);
    return (vf4){fl.x, fl.y, fh.x, fh.y};
}

// raw gather: two adjacent dwords -> one ds_read2_b32 (base is SGPR-resident)
#define GR(sb, dst) { dst.x = xsh[(sb) + loff]; dst.y = xsh[(sb) + loff + 1]; }

// prologue: wave-uniform leaf bases -> SGPRs (readfirstlane), once per kernel
#define RFL(S, J, IDX)                                                        \
    const int sbx##S##_##J = __builtin_amdgcn_readfirstlane(bases[(IDX)].x);  \
    const int sby##S##_##J = __builtin_amdgcn_readfirstlane(bases[(IDX)].y);

// PRE(S): issue stage-S uniforms (7 coef b128) + 8 gathers = EXACTLY 15 DS ops
#define PRE(S)                                                                \
    const vf4 kc##S##_0 = coefs[4*(S)],    kc##S##_1 = coefs[4*(S)+1];        \
    const vf4 kc##S##_2 = coefs[4*(S)+2],  kc##S##_3 = coefs[4*(S)+3];        \
    const vf4 kd##S##_0 = coefs[32+2*(S)], kd##S##_1 = coefs[33+2*(S)];       \
    const vf4 ke##S = coefs[48+(S)];                                          \
    uint2 ga##S##_0, gb##S##_0, ga##S##_1, gb##S##_1;                         \
    uint2 ga##S##_2, gb##S##_2, ga##S##_3, gb##S##_3;                         \
    GR(sbx##S##_0, ga##S##_0); GR(sby##S##_0, gb##S##_0);                     \
    GR(sbx##S##_1, ga##S##_1); GR(sby##S##_1, gb##S##_1);                     \
    GR(sbx##S##_2, ga##S##_2); GR(sby##S##_2, gb##S##_2);                     \
    GR(sbx##S##_3, ga##S##_3); GR(sby##S##_3, gb##S##_3);

// CONSUME(S): cvt + FMA tree for stage S (waits only on PRE(S): lgkmcnt(15))
#define CONSUME(S, FOLD)                                                      \
    vf4 t4_##S;                                                               \
    {                                                                         \
        const vf4 u0 = comb(cvt4(ga##S##_0), cvt4(gb##S##_0), kc##S##_0);     \
        const vf4 u1 = comb(cvt4(ga##S##_1), cvt4(gb##S##_1), kc##S##_1);     \
        const vf4 u2 = comb(cvt4(ga##S##_2), cvt4(gb##S##_2), kc##S##_2);     \
        const vf4 u3 = comb(cvt4(ga##S##_3), cvt4(gb##S##_3), kc##S##_3);     \
        t4_##S = comb(comb(u0, u1, kd##S##_0), comb(u2, u3, kd##S##_1), ke##S); \
        FOLD                                                                  \
    }

__global__ __launch_bounds__(TPB) void logic_conv_kernel(
    const float* __restrict__ x,
    const int*   __restrict__ h_idx,
    const int*   __restrict__ w_idx,
    const int*   __restrict__ c_idx,
    const float* __restrict__ w0, const float* __restrict__ w1,
    const float* __restrict__ w2, const float* __restrict__ w3,
    const float* __restrict__ w4, const float* __restrict__ w5,
    float* __restrict__ out)
{
    __shared__ unsigned int xsh[2 * DWCOPY];   // 26,928 B
    __shared__ vf4  coefs[63];
    __shared__ int2 bases[32];

    const int tid  = threadIdx.x;
    const int blk  = blockIdx.x;
    const int b    = blk >> 6;
    const int k    = (blk >> 1) & 31;
    const int half = blk & 1;
    const int oh0  = half * OHSUB;

    // ---- stage rows [oh0, oh0+34) of x[b] as fp16, two shifted copies ----
    const float* xb = x + b * (Cc * Hh * Ww);
    #pragma unroll
    for (int it = 0; it < 7; ++it) {
        const int flat = it * TPB + tid;
        if (flat < Cc * ROWS * 16) {
            const int c   = flat / (ROWS * 16);
            const int rem = flat - c * (ROWS * 16);
            const int r   = rem >> 4;
            const int w4i = rem & 15;
            const int w0c = w4i << 2;
            const float* src = xb + c * (Hh * Ww) + (oh0 + r) * Ww + w0c;
            const vf4u A = *reinterpret_cast<const vf4u*>(src);
            vf4u Bv;
            if (w4i < 15) Bv = *reinterpret_cast<const vf4u*>(src + 1);
            else          Bv = (vf4u){A.y, A.z, A.w, A.w};
            const int di = c * DWC + r * DWROW + (w0c >> 1);
            xsh[di]              = pkh(A.x, A.y);
            xsh[di + 1]          = pkh(A.z, A.w);
            xsh[DWCOPY + di]     = pkh(Bv.x, Bv.y);
            xsh[DWCOPY + di + 1] = pkh(Bv.z, Bv.w);
        }
    }

    // ---- gather bases (dword index, copy by col parity) ----
    if (tid < 32) {
        const int i0 = (0 * Kk + k) * Ss + tid;
        const int i1 = (1 * Kk + k) * Ss + tid;
        const int wA = w_idx[i0], sA = wA & 1;
        const int wB = w_idx[i1], sB = wB & 1;
        bases[tid] = make_int2(
            sA * DWCOPY + c_idx[i0] * DWC + h_idx[i0] * DWROW + ((wA - sA) >> 1),
            sB * DWCOPY + c_idx[i1] * DWC + h_idx[i1] * DWROW + ((wB - sB) >> 1));
    }

    // ---- per-node coefficients: softmax/LUT folded to 4 floats ----
    if (tid >= 64 && tid < 127) {
        const int t = tid - 64;
        const float* wp; int n;
        if      (t < 32) { wp = w0; n = t;      }
        else if (t < 48) { wp = w1; n = t - 32; }
        else if (t < 56) { wp = w2; n = t - 48; }
        else if (t < 60) { wp = w3; n = t - 56; }
        else if (t < 62) { wp = w4; n = t - 60; }
        else             { wp = w5; n = 0;      }
        const float* lg = wp + (n * Kk + k) * 16;
        float l[16];
        float m = lg[0];
        #pragma unroll
        for (int q = 0; q < 16; ++q) { l[q] = lg[q]; m = fmaxf(m, l[q]); }
        float e[16], s = 0.f;
        #pragma unroll
        for (int q = 0; q < 16; ++q) { e[q] = __expf(l[q] - m); s += e[q]; }
        const float inv = 1.f / s;
        float c0 = 0.f, c1 = 0.f, c2 = 0.f, c3 = 0.f;
        #pragma unroll
        for (int op = 0; op < 16; ++op) {
            if (op & 1) c0 += e[op];
            if (op & 2) c1 += e[op];
            if (op & 4) c2 += e[op];
            if (op & 8) c3 += e[op];
        }
        c0 *= inv; c1 *= inv; c2 *= inv; c3 *= inv;
        coefs[t] = (vf4){c0, c2 - c0, c1 - c0, c0 - c1 - c2 + c3};
    }

    __syncthreads();

    // ---- hoisted loop-invariant uniforms ----
    // leaf bases -> SGPRs (wave-uniform; removes per-stage base reads)
    RFL(0,0, 0) RFL(0,1, 1) RFL(0,2, 2) RFL(0,3, 3)
    RFL(1,0, 4) RFL(1,1, 5) RFL(1,2, 6) RFL(1,3, 7)
    RFL(2,0, 8) RFL(2,1, 9) RFL(2,2,10) RFL(2,3,11)
    RFL(3,0,12) RFL(3,1,13) RFL(3,2,14) RFL(3,3,15)
    RFL(4,0,16) RFL(4,1,17) RFL(4,2,18) RFL(4,3,19)
    RFL(5,0,20) RFL(5,1,21) RFL(5,2,22) RFL(5,3,23)
    RFL(6,0,24) RFL(6,1,25) RFL(6,2,26) RFL(6,3,27)
    RFL(7,0,28) RFL(7,1,29) RFL(7,2,30) RFL(7,3,31)
    // fold coefs held in VGPRs for the whole kernel
    const vf4 kf56 = coefs[56], kf57 = coefs[57], kf58 = coefs[58];
    const vf4 kf59 = coefs[59], kf60 = coefs[60], kf61 = coefs[61];
    const vf4 kf62 = coefs[62];

    // ---- main: software-pipelined 8-stage tree, one 4-px group/thread ----
    float* const outb = out + (b * Kk + k) * Pp + oh0 * OWw;
    #pragma unroll 1
    for (int it = 0; it < 2; ++it) {
        const int g = it * TPB + tid;
        if (g < NGRP) {
            const int oh   = g % OHSUB;
            const int owg  = g / OHSUB;
            const int loff = oh * DWROW + (owg << 1);

            vf4 t8a, t8b, t16a, t8a2, t8b2, t16b, y;

            PRE(0)
            PRE(1)
            SB;
            CONSUME(0, )
            PRE(2)
            SB;
            CONSUME(1, t8a = comb(t4_0, t4_1, kf56);)
            PRE(3)
            SB;
            CONSUME(2, )
            PRE(4)
            SB;
            CONSUME(3, t8b = comb(t4_2, t4_3, kf57);
                       t16a = comb(t8a, t8b, kf60);)
            PRE(5)
            SB;
            CONSUME(4, )
            PRE(6)
            SB;
            CONSUME(5, t8a2 = comb(t4_4, t4_5, kf58);)
            PRE(7)
            SB;
            CONSUME(6, )
            SB;
            CONSUME(7, t8b2 = comb(t4_6, t4_7, kf59);
                       t16b = comb(t8a2, t8b2, kf61);
                       y = comb(t16a, t16b, kf62);)
            SB;

            *reinterpret_cast<vf4*>(outb + oh * OWw + (owg << 2)) = y;
        }
    }
}

extern "C" void kernel_launch(void* const* d_in, const int* in_sizes, int n_in,
                              void* d_out, int out_size, void* d_ws, size_t ws_size,
                              hipStream_t stream) {
    const float* x     = (const float*)d_in[0];
    const int*   h_idx = (const int*)d_in[1];
    const int*   w_idx = (const int*)d_in[2];
    const int*   c_idx = (const int*)d_in[3];
    const float* w0    = (const float*)d_in[4];
    const float* w1    = (const float*)d_in[5];
    const float* w2    = (const float*)d_in[6];
    const float* w3    = (const float*)d_in[7];
    const float* w4    = (const float*)d_in[8];
    const float* w5    = (const float*)d_in[9];
    float* out = (float*)d_out;

    dim3 grid(Bb * Kk * 2);   // 1024 blocks: (b, k, row-half)
    dim3 block(TPB);
    hipLaunchKernelGGL(logic_conv_kernel, grid, block, 0, stream,
                       x, h_idx, w_idx, c_idx, w0, w1, w2, w3, w4, w5, out);
}

// Round 13
// 20.715 us; speedup vs baseline: 1.2576x; 1.2576x over previous
//
#include <hip/hip_runtime.h>
#include <hip/hip_fp16.h>
#include <math.h>

// Problem constants (match reference)
#define Bb   16
#define Cc   3
#define Hh   64
#define Ww   64
#define Kk   32
#define Ss   32
#define OHh  60
#define OWw  60
#define Pp   3600
#define ROWS 34            // staged rows per block: 30 output rows + R-1
#define OHSUB 30
#define NGRP 450
#define TPB  256

// fp16 LDS layout (dword units): row = 33 dwords. Bank stride/row = 1 ->
// oh-major lanes conflict-free. Two copies (shift 0/1 col): every 4-px
// gather is one ds_read2_b32 (2 adjacent dwords), and those dwords are
// directly __half2 operands for v_pk_fma_f16 (no converts).
#define DWROW  33
#define DWC    (ROWS * DWROW)   // 1122 dwords per channel
#define DWCOPY (Cc * DWC)       // 3366 dwords per copy

typedef float vf4 __attribute__((ext_vector_type(4)));
typedef float vf4u __attribute__((ext_vector_type(4), aligned(4)));

#define SB __builtin_amdgcn_sched_barrier(0)

static __device__ __forceinline__ unsigned int pkh(float lo, float hi) {
    __half2 h = __floats2half2_rn(lo, hi);
    return *reinterpret_cast<unsigned int*>(&h);
}
static __device__ __forceinline__ __half2 bc(unsigned int u) {
    return *reinterpret_cast<__half2*>(&u);
}
static __device__ __forceinline__ unsigned int bits(__half2 h) {
    return *reinterpret_cast<unsigned int*>(&h);
}

// fp16 combine on 4 px (2 half2): y = c0 + a*dA + b*dB + a*b*dAB
// coef uint4 = pre-broadcast half2: {c0,c0},{dA,dA},{dB,dB},{dAB,dAB}
static __device__ __forceinline__ uint2 comb2(uint2 a, uint2 b, uint4 c) {
    const __half2 cc0 = bc(c.x), ccA = bc(c.y), ccB = bc(c.z), ccAB = bc(c.w);
    const __half2 tx = __hfma2(bc(b.x), ccAB, ccA);
    const __half2 ty = __hfma2(bc(b.y), ccAB, ccA);
    const __half2 ux = __hfma2(bc(b.x), ccB, cc0);
    const __half2 uy = __hfma2(bc(b.y), ccB, cc0);
    uint2 r;
    r.x = bits(__hfma2(bc(a.x), tx, ux));
    r.y = bits(__hfma2(bc(a.y), ty, uy));
    return r;
}

// raw gather: two adjacent dwords -> one ds_read2_b32 (base is SGPR-resident)
#define GR(sb, dst) { dst.x = xsh[(sb) + loff]; dst.y = xsh[(sb) + loff + 1]; }

// prologue: wave-uniform leaf bases -> SGPRs (readfirstlane), once per kernel
#define RFL(S, J, IDX)                                                        \
    const int sbx##S##_##J = __builtin_amdgcn_readfirstlane(bases[(IDX)].x);  \
    const int sby##S##_##J = __builtin_amdgcn_readfirstlane(bases[(IDX)].y);

// issue stage-S gathers (8 ds_read2_b32)
#define PREG(S)                                                               \
    uint2 ga##S##_0, gb##S##_0, ga##S##_1, gb##S##_1;                         \
    uint2 ga##S##_2, gb##S##_2, ga##S##_3, gb##S##_3;                         \
    GR(sbx##S##_0, ga##S##_0); GR(sby##S##_0, gb##S##_0);                     \
    GR(sbx##S##_1, ga##S##_1); GR(sby##S##_1, gb##S##_1);                     \
    GR(sbx##S##_2, ga##S##_2); GR(sby##S##_2, gb##S##_2);                     \
    GR(sbx##S##_3, ga##S##_3); GR(sby##S##_3, gb##S##_3);

// read stage-S coefficients (7 uniform b128)
#define COEF(S)                                                               \
    const uint4 kc##S##_0 = coefb[4*(S)],    kc##S##_1 = coefb[4*(S)+1];      \
    const uint4 kc##S##_2 = coefb[4*(S)+2],  kc##S##_3 = coefb[4*(S)+3];      \
    const uint4 kd##S##_0 = coefb[32+2*(S)], kd##S##_1 = coefb[33+2*(S)];     \
    const uint4 ke##S = coefb[48+(S)];

// fp16 FMA tree for stage S
#define FMAS(S, FOLD)                                                         \
    uint2 t4_##S;                                                             \
    {                                                                         \
        const uint2 u0 = comb2(ga##S##_0, gb##S##_0, kc##S##_0);              \
        const uint2 u1 = comb2(ga##S##_1, gb##S##_1, kc##S##_1);              \
        const uint2 u2 = comb2(ga##S##_2, gb##S##_2, kc##S##_2);              \
        const uint2 u3 = comb2(ga##S##_3, gb##S##_3, kc##S##_3);              \
        t4_##S = comb2(comb2(u0, u1, kd##S##_0), comb2(u2, u3, kd##S##_1), ke##S); \
        FOLD                                                                  \
    }

__global__ __launch_bounds__(TPB) void logic_conv_kernel(
    const float* __restrict__ x,
    const int*   __restrict__ h_idx,
    const int*   __restrict__ w_idx,
    const int*   __restrict__ c_idx,
    const float* __restrict__ w0, const float* __restrict__ w1,
    const float* __restrict__ w2, const float* __restrict__ w3,
    const float* __restrict__ w4, const float* __restrict__ w5,
    float* __restrict__ out)
{
    __shared__ unsigned int xsh[2 * DWCOPY];   // 26,928 B
    __shared__ uint4 coefb[63];                // pre-broadcast half2 coefs
    __shared__ int2  bases[32];

    const int tid  = threadIdx.x;
    const int blk  = blockIdx.x;
    const int b    = blk >> 6;
    const int k    = (blk >> 1) & 31;
    const int half = blk & 1;
    const int oh0  = half * OHSUB;

    // ---- stage rows [oh0, oh0+34) of x[b] as fp16, two shifted copies ----
    const float* xb = x + b * (Cc * Hh * Ww);
    #pragma unroll
    for (int it = 0; it < 7; ++it) {
        const int flat = it * TPB + tid;
        if (flat < Cc * ROWS * 16) {
            const int c   = flat / (ROWS * 16);
            const int rem = flat - c * (ROWS * 16);
            const int r   = rem >> 4;
            const int w4i = rem & 15;
            const int w0c = w4i << 2;
            const float* src = xb + c * (Hh * Ww) + (oh0 + r) * Ww + w0c;
            const vf4u A = *reinterpret_cast<const vf4u*>(src);
            vf4u Bv;
            if (w4i < 15) Bv = *reinterpret_cast<const vf4u*>(src + 1);
            else          Bv = (vf4u){A.y, A.z, A.w, A.w};
            const int di = c * DWC + r * DWROW + (w0c >> 1);
            xsh[di]              = pkh(A.x, A.y);
            xsh[di + 1]          = pkh(A.z, A.w);
            xsh[DWCOPY + di]     = pkh(Bv.x, Bv.y);
            xsh[DWCOPY + di + 1] = pkh(Bv.z, Bv.w);
        }
    }

    // ---- gather bases (dword index, copy by col parity) ----
    if (tid < 32) {
        const int i0 = (0 * Kk + k) * Ss + tid;
        const int i1 = (1 * Kk + k) * Ss + tid;
        const int wA = w_idx[i0], sA = wA & 1;
        const int wB = w_idx[i1], sB = wB & 1;
        bases[tid] = make_int2(
            sA * DWCOPY + c_idx[i0] * DWC + h_idx[i0] * DWROW + ((wA - sA) >> 1),
            sB * DWCOPY + c_idx[i1] * DWC + h_idx[i1] * DWROW + ((wB - sB) >> 1));
    }

    // ---- per-node coefficients: softmax/LUT folded, packed as bcast half2 ----
    if (tid >= 64 && tid < 127) {
        const int t = tid - 64;
        const float* wp; int n;
        if      (t < 32) { wp = w0; n = t;      }
        else if (t < 48) { wp = w1; n = t - 32; }
        else if (t < 56) { wp = w2; n = t - 48; }
        else if (t < 60) { wp = w3; n = t - 56; }
        else if (t < 62) { wp = w4; n = t - 60; }
        else             { wp = w5; n = 0;      }
        const float* lg = wp + (n * Kk + k) * 16;
        float l[16];
        float m = lg[0];
        #pragma unroll
        for (int q = 0; q < 16; ++q) { l[q] = lg[q]; m = fmaxf(m, l[q]); }
        float e[16], s = 0.f;
        #pragma unroll
        for (int q = 0; q < 16; ++q) { e[q] = __expf(l[q] - m); s += e[q]; }
        const float inv = 1.f / s;
        float c0 = 0.f, c1 = 0.f, c2 = 0.f, c3 = 0.f;
        #pragma unroll
        for (int op = 0; op < 16; ++op) {
            if (op & 1) c0 += e[op];
            if (op & 2) c1 += e[op];
            if (op & 4) c2 += e[op];
            if (op & 8) c3 += e[op];
        }
        c0 *= inv; c1 *= inv; c2 *= inv; c3 *= inv;
        const float dA = c2 - c0, dB = c1 - c0, dAB = c0 - c1 - c2 + c3;
        coefb[t] = make_uint4(pkh(c0, c0), pkh(dA, dA), pkh(dB, dB), pkh(dAB, dAB));
    }

    __syncthreads();

    // ---- hoisted wave-uniform leaf bases -> SGPRs ----
    RFL(0,0, 0) RFL(0,1, 1) RFL(0,2, 2) RFL(0,3, 3)
    RFL(1,0, 4) RFL(1,1, 5) RFL(1,2, 6) RFL(1,3, 7)
    RFL(2,0, 8) RFL(2,1, 9) RFL(2,2,10) RFL(2,3,11)
    RFL(3,0,12) RFL(3,1,13) RFL(3,2,14) RFL(3,3,15)
    RFL(4,0,16) RFL(4,1,17) RFL(4,2,18) RFL(4,3,19)
    RFL(5,0,20) RFL(5,1,21) RFL(5,2,22) RFL(5,3,23)
    RFL(6,0,24) RFL(6,1,25) RFL(6,2,26) RFL(6,3,27)
    RFL(7,0,28) RFL(7,1,29) RFL(7,2,30) RFL(7,3,31)

    // ---- main: fp16 software-pipelined 8-stage tree, 4 px/thread ----
    float* const outb = out + (b * Kk + k) * Pp + oh0 * OWw;
    #pragma unroll 1
    for (int it = 0; it < 2; ++it) {
        const int g = it * TPB + tid;
        if (g < NGRP) {
            const int oh   = g % OHSUB;
            const int owg  = g / OHSUB;
            const int loff = oh * DWROW + (owg << 1);

            uint2 t8a, t8b, t16a, t8a2, t8b2, t16b, y;

            PREG(0)
            COEF(0) PREG(1) SB;
            FMAS(0, )
            COEF(1) PREG(2) SB;
            FMAS(1, t8a = comb2(t4_0, t4_1, coefb[56]);)
            COEF(2) PREG(3) SB;
            FMAS(2, )
            COEF(3) PREG(4) SB;
            FMAS(3, t8b = comb2(t4_2, t4_3, coefb[57]);
                    t16a = comb2(t8a, t8b, coefb[60]);)
            COEF(4) PREG(5) SB;
            FMAS(4, )
            COEF(5) PREG(6) SB;
            FMAS(5, t8a2 = comb2(t4_4, t4_5, coefb[58]);)
            COEF(6) PREG(7) SB;
            FMAS(6, )
            COEF(7) SB;
            FMAS(7, t8b2 = comb2(t4_6, t4_7, coefb[59]);
                    t16b = comb2(t8a2, t8b2, coefb[61]);
                    y = comb2(t16a, t16b, coefb[62]);)
            SB;

            // fp16 -> f32 only at the output store
            const float2 ylo = __half22float2(bc(y.x));
            const float2 yhi = __half22float2(bc(y.y));
            *reinterpret_cast<vf4*>(outb + oh * OWw + (owg << 2)) =
                (vf4){ylo.x, ylo.y, yhi.x, yhi.y};
        }
    }
}

extern "C" void kernel_launch(void* const* d_in, const int* in_sizes, int n_in,
                              void* d_out, int out_size, void* d_ws, size_t ws_size,
                              hipStream_t stream) {
    const float* x     = (const float*)d_in[0];
    const int*   h_idx = (const int*)d_in[1];
    const int*   w_idx = (const int*)d_in[2];
    const int*   c_idx = (const int*)d_in[3];
    const float* w0    = (const float*)d_in[4];
    const float* w1    = (const float*)d_in[5];
    const float* w2    = (const float*)d_in[6];
    const float* w3    = (const float*)d_in[7];
    const float* w4    = (const float*)d_in[8];
    const float* w5    = (const float*)d_in[9];
    float* out = (float*)d_out;

    dim3 grid(Bb * Kk * 2);   // 1024 blocks: (b, k, row-half)
    dim3 block(TPB);
    hipLaunchKernelGGL(logic_conv_kernel, grid, block, 0, stream,
                       x, h_idx, w_idx, c_idx, w0, w1, w2, w3, w4, w5, out);
}